// Round 4
// baseline (706.289 us; speedup 1.0000x reference)
//
#include <hip/hip_runtime.h>
#include <math.h>

// Probabilistic Slot Attention, B=8 N=4096 K=8 D=256, 3 iterations.
// Round 4: Round-3 structure (2 dispatches) but the cooperative launch is
// replaced by a manual device-scope atomic grid barrier at 256 blocks
// (1 block/CU -> co-residency guaranteed for any VGPR/LDS; no cooperative
// launch validator to fail). Iteration numerics are the exact Round-2
// passing forms (diff-form gll, same init/prep); attn stored last iter only.

#define Bd 8
#define Nd 4096
#define Kd 8
#define Dd 256
#define Md (Bd*Nd)              // 32768 rows
#define NITER 3
#define EPSf 1e-8f
#define LNEPS 1e-5f
#define NCH 32                  // chunks per batch
#define CHN 128                 // n per chunk
#define GRIDN 256               // k_iter grid size
#define LOGNORM -235.24826450039617f   // -0.5*256*log(2*pi)

typedef float f32x4 __attribute__((ext_vector_type(4)));
typedef short bf16x8 __attribute__((ext_vector_type(8)));
typedef unsigned short ushort_t;

// workspace float offsets
#define KEYS_OFF 0
#define VALS_OFF (Md*Dd)                // 8388608
#define Q_OFF    (2*Md*Dd)              // 16777216
#define W_OFF    (Q_OFF + 16384)
#define C2_OFF   (W_OFF + 16384)
#define CMX_OFF  (C2_OFF + 64)
#define CSM_OFF  (CMX_OFF + 2048)
#define PMU_OFF  (CSM_OFF + 2048)
#define PS2_OFF  (PMU_OFF + 524288)
#define CNT_OFF  (PS2_OFF + 524288)

__device__ __forceinline__ ushort_t f2bf(float f) {
    unsigned u = __float_as_uint(f);
    return (ushort_t)((u + 0x7FFFu + ((u >> 16) & 1u)) >> 16);   // RNE
}
__device__ __forceinline__ float b2f(ushort_t h) {
    return __uint_as_float(((unsigned)h) << 16);
}

// Device-scope grid barrier: monotone counter, no reset. All GRIDN blocks
// must be co-resident (1 block/CU at grid=256 -> always true).
__device__ __forceinline__ void gbar(unsigned* cnt, unsigned target) {
    __syncthreads();
    if (threadIdx.x == 0) {
        __threadfence();
        __hip_atomic_fetch_add(cnt, 1u, __ATOMIC_ACQ_REL, __HIP_MEMORY_SCOPE_AGENT);
        while (__hip_atomic_load(cnt, __ATOMIC_ACQUIRE, __HIP_MEMORY_SCOPE_AGENT) < target)
            __builtin_amdgcn_s_sleep(8);
    }
    __syncthreads();
}

// ---------------------------------------------------------------------------
// GEMM: C[32768 x 512] = LN(emb) x [Wk||Wv]^T via split-bf16 MFMA.
// Fused LN-stats pre-pass + in-block W f32->bf16 hi/lo conversion.
// Block tile 128(M) x 256(N), BK=32, 4 waves 2x2, XOR-swizzled LDS granules.
__global__ __launch_bounds__(256, 2) void k_gemm(
        const float* __restrict__ emb, const float* __restrict__ Wk,
        const float* __restrict__ Wv, const float* __restrict__ lns,
        const float* __restrict__ lnb, float* __restrict__ keys,
        float* __restrict__ vals, unsigned* __restrict__ cnt) {
    __shared__ ushort_t Ah[128 * 32], Al[128 * 32];   // 8 KB each
    __shared__ ushort_t Bh[256 * 32], Bl[256 * 32];   // 16 KB each
    __shared__ float m_s[128], r_s[128];
    const int tid = threadIdx.x, lane = tid & 63, wave = tid >> 6;
    const int row0 = blockIdx.x * 128;
    const int cb = blockIdx.y;                 // 0 -> keys, 1 -> vals
    const int wm = wave >> 1, wn = wave & 1;

    if (blockIdx.x == 0 && cb == 0 && tid == 0) *cnt = 0u;  // barrier counter init

    // ---- LN stats pre-pass: wave handles 32 rows ----
    for (int rr = 0; rr < 32; ++rr) {
        const int r = wave * 32 + rr;
        const float4 e4 = ((const float4*)(emb + (size_t)(row0 + r) * Dd))[lane];
        float s = e4.x + e4.y + e4.z + e4.w;
        #pragma unroll
        for (int off = 32; off; off >>= 1) s += __shfl_xor(s, off);
        const float m = s * (1.0f / 256.0f);
        const float dx = e4.x - m, dy = e4.y - m, dz = e4.z - m, dw = e4.w - m;
        float ss = dx * dx + dy * dy + dz * dz + dw * dw;
        #pragma unroll
        for (int off = 32; off; off >>= 1) ss += __shfl_xor(ss, off);
        if (lane == 0) {
            m_s[r] = m;
            r_s[r] = 1.0f / sqrtf(ss * (1.0f / 256.0f) + LNEPS);
        }
    }
    __syncthreads();

    f32x4 acc[4][8];
    #pragma unroll
    for (int a = 0; a < 4; ++a)
        #pragma unroll
        for (int b = 0; b < 8; ++b) acc[a][b] = (f32x4)(0.0f);

    for (int jb = 0; jb < 256; jb += 32) {
        // ---- A staging: LN + split, swizzled granules ----
        #pragma unroll
        for (int i = 0; i < 2; ++i) {
            const int p = tid + i * 256;            // granule position 0..511
            const int r = p >> 2, g = p & 3;
            const float* src = emb + (size_t)(row0 + r) * Dd + jb + g * 8;
            const float4 e0 = ((const float4*)src)[0];
            const float4 e1 = ((const float4*)src)[1];
            const float m  = m_s[r];
            const float rs = r_s[r];
            const float4 sc0 = ((const float4*)(lns + jb + g * 8))[0];
            const float4 sc1 = ((const float4*)(lns + jb + g * 8))[1];
            const float4 bi0 = ((const float4*)(lnb + jb + g * 8))[0];
            const float4 bi1 = ((const float4*)(lnb + jb + g * 8))[1];
            float x[8];
            x[0] = (e0.x - m) * rs * sc0.x + bi0.x;
            x[1] = (e0.y - m) * rs * sc0.y + bi0.y;
            x[2] = (e0.z - m) * rs * sc0.z + bi0.z;
            x[3] = (e0.w - m) * rs * sc0.w + bi0.w;
            x[4] = (e1.x - m) * rs * sc1.x + bi1.x;
            x[5] = (e1.y - m) * rs * sc1.y + bi1.y;
            x[6] = (e1.z - m) * rs * sc1.z + bi1.z;
            x[7] = (e1.w - m) * rs * sc1.w + bi1.w;
            bf16x8 hv, lv;
            #pragma unroll
            for (int j = 0; j < 8; ++j) {
                const ushort_t h = f2bf(x[j]);
                hv[j] = (short)h;
                lv[j] = (short)f2bf(x[j] - b2f(h));
            }
            const int dst = r * 32 + ((g ^ ((r >> 1) & 3)) << 3);  // ushort idx
            *(bf16x8*)&Ah[dst] = hv;
            *(bf16x8*)&Al[dst] = lv;
        }
        // ---- B staging: read f32 W, convert to hi/lo, swizzled ds_write ----
        {
            const float* Wrow = (cb ? Wv : Wk) + (size_t)tid * 256 + jb;
            float4 wv[8];
            #pragma unroll
            for (int q = 0; q < 8; ++q) wv[q] = ((const float4*)Wrow)[q];
            #pragma unroll
            for (int g = 0; g < 4; ++g) {
                bf16x8 hv, lv;
                const float* f = (const float*)&wv[g * 2];
                #pragma unroll
                for (int e = 0; e < 8; ++e) {
                    const ushort_t h = f2bf(f[e]);
                    hv[e] = (short)h;
                    lv[e] = (short)f2bf(f[e] - b2f(h));
                }
                const int dst = tid * 32 + ((g ^ ((tid >> 1) & 3)) << 3);
                *(bf16x8*)&Bh[dst] = hv;
                *(bf16x8*)&Bl[dst] = lv;
            }
        }
        __syncthreads();

        // ---- compute ----
        bf16x8 bhf[8], blf[8];
        #pragma unroll
        for (int ni = 0; ni < 8; ++ni) {
            const int c = wn * 128 + ni * 16 + (lane & 15);
            const int g = lane >> 4;
            const int off = c * 32 + ((g ^ ((c >> 1) & 3)) << 3);
            bhf[ni] = *(const bf16x8*)&Bh[off];
            blf[ni] = *(const bf16x8*)&Bl[off];
        }
        #pragma unroll
        for (int mi = 0; mi < 4; ++mi) {
            const int rr = wm * 64 + mi * 16 + (lane & 15);
            const int g = lane >> 4;
            const int off = rr * 32 + ((g ^ ((rr >> 1) & 3)) << 3);
            const bf16x8 ah = *(const bf16x8*)&Ah[off];
            const bf16x8 al = *(const bf16x8*)&Al[off];
            #pragma unroll
            for (int ni = 0; ni < 8; ++ni) {
                acc[mi][ni] = __builtin_amdgcn_mfma_f32_16x16x32_bf16(ah, bhf[ni], acc[mi][ni], 0, 0, 0);
                acc[mi][ni] = __builtin_amdgcn_mfma_f32_16x16x32_bf16(ah, blf[ni], acc[mi][ni], 0, 0, 0);
                acc[mi][ni] = __builtin_amdgcn_mfma_f32_16x16x32_bf16(al, bhf[ni], acc[mi][ni], 0, 0, 0);
            }
        }
        __syncthreads();
    }
    // ---- epilogue: C/D layout col=lane&15, row=(lane>>4)*4+reg ----
    float* outp = (cb == 0) ? keys : vals;
    #pragma unroll
    for (int mi = 0; mi < 4; ++mi) {
        const int rbase = row0 + wm * 64 + mi * 16 + ((lane >> 4) << 2);
        #pragma unroll
        for (int ni = 0; ni < 8; ++ni) {
            const int col = wn * 128 + ni * 16 + (lane & 15);
            #pragma unroll
            for (int rg = 0; rg < 4; ++rg)
                outp[(size_t)(rbase + rg) * Dd + col] = acc[mi][ni][rg];
        }
    }
}

// ---------------------------------------------------------------------------
// Iteration kernel: 256 blocks x 256 threads, manual grid barriers.
// Block (b = blk>>5, c = blk&31) owns 128 n. Per iteration:
//  A: gll (regs, diff form) + per-chunk max/sumexp  -> barrier
//  B: global softmax combine -> attn (LDS; d_out on last iter) -> mu/s2
//     partials                                      -> barrier
//  C: blocks 0..63 reduce partials -> w,c2 (or slots_out) -> barrier
__global__ __launch_bounds__(256) void k_iter(
        const float* __restrict__ keys, const float* __restrict__ vals,
        const float* __restrict__ mu0, const float* __restrict__ lsig,
        const float* __restrict__ nz0, const float* __restrict__ Wq,
        const float* __restrict__ nzf, float* __restrict__ ws,
        float* __restrict__ out) {
    __shared__ float comb_s[16 * CHN];   // 8 KB  [dp*8+k][nloc]
    __shared__ float a_t[CHN * 8];       // 4 KB  [n][k]
    __shared__ float s_s[256], red1[256];

    float* qg  = ws + Q_OFF;
    float* wg  = ws + W_OFF;
    float* c2g = ws + C2_OFF;
    float* cmx = ws + CMX_OFF;
    float* csm = ws + CSM_OFF;
    float* pmu = ws + PMU_OFF;
    float* ps2 = ws + PS2_OFF;
    unsigned* cnt = (unsigned*)(ws + CNT_OFF);
    float* attn_out = out + Bd * Kd * Dd;

    const int blk = blockIdx.x, tid = threadIdx.x;
    const int b = blk >> 5, c = blk & 31, n0 = c * CHN;
    const int k8 = tid >> 5, j = tid & 31;
    unsigned ep = 0;

    // ---- init: blocks 0..63 = (b,k): slots, q, w, c2 (Round-2 k_init) ----
    if (blk < 64) {
        const int kk = blk & 7, d = tid;
        const float sg = expf(lsig[kk * 256 + d]);
        s_s[d] = mu0[kk * 256 + d] + sg * nz0[(size_t)blk * 256 + d];
        wg[(size_t)blk * 256 + d] = 1.0f / (sg * sg + EPSf);
        red1[d] = logf(fabsf(sg) + EPSf);
        __syncthreads();
        float q = 0.0f;
        const float4* Wr = (const float4*)(Wq + (size_t)d * 256);
        const float4* sp = (const float4*)s_s;
        #pragma unroll 8
        for (int t = 0; t < 64; ++t) {
            const float4 w4 = Wr[t], s4 = sp[t];
            q += w4.x * s4.x + w4.y * s4.y + w4.z * s4.z + w4.w * s4.w;
        }
        qg[(size_t)blk * 256 + d] = q;
        __syncthreads();
        for (int s = 128; s; s >>= 1) {
            if (d < s) red1[d] += red1[d + s];
            __syncthreads();
        }
        if (d == 0) c2g[blk] = LOGNORM - 0.5f * red1[0];
    }
    gbar(cnt, ++ep * GRIDN);

    float g0 = 0.0f, g1 = 0.0f, g2 = 0.0f, g3 = 0.0f;
    for (int it = 0; it < NITER; ++it) {
        // ================= phase A: gll (diff form) + chunk stats =========
        {
            const int nloc = tid & 127, dp = tid >> 7;
            const float4* krow = (const float4*)(keys + ((size_t)b * Nd + n0 + nloc) * Dd + dp * 128);
            const float4* qb = (const float4*)(qg + (size_t)b * 2048 + dp * 128);
            const float4* wb = (const float4*)(wg + (size_t)b * 2048 + dp * 128);
            float acc[8];
            #pragma unroll
            for (int kk = 0; kk < 8; ++kk) acc[kk] = 0.0f;
            for (int dq = 0; dq < 32; ++dq) {
                const float4 k4 = krow[dq];
                #pragma unroll
                for (int kk = 0; kk < 8; ++kk) {
                    const float4 q4 = qb[kk * 64 + dq];
                    const float4 w4 = wb[kk * 64 + dq];
                    float t;
                    t = k4.x - q4.x; acc[kk] += t * t * w4.x;
                    t = k4.y - q4.y; acc[kk] += t * t * w4.y;
                    t = k4.z - q4.z; acc[kk] += t * t * w4.z;
                    t = k4.w - q4.w; acc[kk] += t * t * w4.w;
                }
            }
            #pragma unroll
            for (int kk = 0; kk < 8; ++kk) comb_s[(dp * 8 + kk) * CHN + nloc] = acc[kk];
        }
        __syncthreads();
        {
            const float c2 = c2g[b * 8 + k8];
            const float4 ca = *(const float4*)&comb_s[k8 * CHN + j * 4];
            const float4 cb = *(const float4*)&comb_s[(8 + k8) * CHN + j * 4];
            g0 = fminf(fmaxf(c2 - 0.5f * (ca.x + cb.x), -10000.0f), 10000.0f);
            g1 = fminf(fmaxf(c2 - 0.5f * (ca.y + cb.y), -10000.0f), 10000.0f);
            g2 = fminf(fmaxf(c2 - 0.5f * (ca.z + cb.z), -10000.0f), 10000.0f);
            g3 = fminf(fmaxf(c2 - 0.5f * (ca.w + cb.w), -10000.0f), 10000.0f);
            float m = fmaxf(fmaxf(g0, g1), fmaxf(g2, g3));
            #pragma unroll
            for (int off = 16; off; off >>= 1) m = fmaxf(m, __shfl_xor(m, off));
            float se = expf(g0 - m) + expf(g1 - m) + expf(g2 - m) + expf(g3 - m);
            #pragma unroll
            for (int off = 16; off; off >>= 1) se += __shfl_xor(se, off);
            if (j == 0) {
                cmx[(b * 8 + k8) * NCH + c] = m;
                csm[(b * 8 + k8) * NCH + c] = se;
            }
        }
        gbar(cnt, ++ep * GRIDN);

        // ============ phase B: softmax finalize + attn + mu/s2 ============
        {
            float M = cmx[(b * 8 + k8) * NCH + j];
            float S = csm[(b * 8 + k8) * NCH + j];
            #pragma unroll
            for (int off = 16; off; off >>= 1) {
                const float Mo = __shfl_xor(M, off), So = __shfl_xor(S, off);
                const float Mn = fmaxf(M, Mo);
                S = S * expf(M - Mn) + So * expf(Mo - Mn);
                M = Mn;
            }
            const float inv = 1.0f / S;
            const float a0 = expf(g0 - M) * inv;
            const float a1 = expf(g1 - M) * inv;
            const float a2 = expf(g2 - M) * inv;
            const float a3 = expf(g3 - M) * inv;
            a_t[(j * 4 + 0) * 8 + k8] = a0;
            a_t[(j * 4 + 1) * 8 + k8] = a1;
            a_t[(j * 4 + 2) * 8 + k8] = a2;
            a_t[(j * 4 + 3) * 8 + k8] = a3;
            if (it == NITER - 1) {
                float4 o; o.x = a0; o.y = a1; o.z = a2; o.w = a3;
                *(float4*)&attn_out[(size_t)(b * 8 + k8) * Nd + n0 + j * 4] = o;
            }
        }
        __syncthreads();
        {
            const int d = tid;
            const float* vb = vals + ((size_t)b * Nd + n0) * Dd + d;
            float amu[8], as2[8];
            #pragma unroll
            for (int kk = 0; kk < 8; ++kk) { amu[kk] = 0.0f; as2[kk] = 0.0f; }
            for (int nn = 0; nn < CHN; ++nn) {
                const float v = vb[(size_t)nn * Dd];
                const float v2 = v * v;
                const float4 aa = *(const float4*)&a_t[nn * 8];
                const float4 ab = *(const float4*)&a_t[nn * 8 + 4];
                amu[0] += aa.x * v; as2[0] += aa.x * v2;
                amu[1] += aa.y * v; as2[1] += aa.y * v2;
                amu[2] += aa.z * v; as2[2] += aa.z * v2;
                amu[3] += aa.w * v; as2[3] += aa.w * v2;
                amu[4] += ab.x * v; as2[4] += ab.x * v2;
                amu[5] += ab.y * v; as2[5] += ab.y * v2;
                amu[6] += ab.z * v; as2[6] += ab.z * v2;
                amu[7] += ab.w * v; as2[7] += ab.w * v2;
            }
            #pragma unroll
            for (int kk = 0; kk < 8; ++kk) {
                const size_t o = (((size_t)(b * NCH + c)) * 8 + kk) * 256 + d;
                pmu[o] = amu[kk];
                ps2[o] = as2[kk];
            }
        }
        gbar(cnt, ++ep * GRIDN);

        // ========== phase C: reduce partials -> w, c2 / slots_out =========
        if (blk < 64) {
            const int d = tid, bb = blk >> 3, kk = blk & 7;
            float mu = 0.0f, s2 = 0.0f;
            for (int cc = 0; cc < NCH; ++cc) {
                const size_t o = (((size_t)(bb * NCH + cc)) * 8 + kk) * 256 + d;
                mu += pmu[o];
                s2 += ps2[o];
            }
            const float sg = s2 - mu * mu;
            if (it == NITER - 1) {
                out[(size_t)blk * 256 + d] =
                    mu + fmaxf(fabsf(sg), EPSf) * nzf[(size_t)blk * 256 + d];
            } else {
                wg[(size_t)blk * 256 + d] = 1.0f / (sg * sg + EPSf);
                red1[d] = logf(fabsf(sg) + EPSf);
                __syncthreads();
                for (int s = 128; s; s >>= 1) {
                    if (d < s) red1[d] += red1[d + s];
                    __syncthreads();
                }
                if (d == 0) c2g[blk] = LOGNORM - 0.5f * red1[0];
            }
        }
        if (it < NITER - 1) gbar(cnt, ++ep * GRIDN);
    }
}

// ---------------------------------------------------------------------------
extern "C" void kernel_launch(void* const* d_in, const int* in_sizes, int n_in,
                              void* d_out, int out_size, void* d_ws, size_t ws_size,
                              hipStream_t stream) {
    const float* emb  = (const float*)d_in[0];
    const float* mu0  = (const float*)d_in[1];
    const float* lsig = (const float*)d_in[2];
    // d_in[3] mixing_coeffs: constant per (b,k), cancels in softmax over N.
    const float* Wq   = (const float*)d_in[4];
    const float* Wk   = (const float*)d_in[5];
    const float* Wv   = (const float*)d_in[6];
    const float* lns  = (const float*)d_in[7];
    const float* lnb  = (const float*)d_in[8];
    const float* nz0  = (const float*)d_in[9];
    const float* nzf  = (const float*)d_in[10];
    // d_in[11] num_iterations == 3.

    float* ws  = (float*)d_ws;
    float* out = (float*)d_out;
    float* keys = ws + KEYS_OFF;
    float* vals = ws + VALS_OFF;
    unsigned* cnt = (unsigned*)(ws + CNT_OFF);

    k_gemm<<<dim3(256, 2), 256, 0, stream>>>(emb, Wk, Wv, lns, lnb, keys, vals, cnt);
    k_iter<<<GRIDN, 256, 0, stream>>>(keys, vals, mu0, lsig, nz0, Wq, nzf, ws, out);
    (void)in_sizes; (void)n_in; (void)out_size; (void)ws_size;
}

// Round 5
// 691.810 us; speedup vs baseline: 1.0209x; 1.0209x over previous
//
#include <hip/hip_runtime.h>
#include <math.h>

// Probabilistic Slot Attention, B=8 N=4096 K=8 D=256, 3 iterations.
// Round 5: cheap grid barrier. R4's agent-scope acquire spin invalidated
// L1/L2 per poll (574us, FETCH 107MB, VALUBusy 4.5%). Now: relaxed/system
// bypass-load spin (no cache maintenance) + one release/system fetch_add
// (wbl2) per block per barrier. Cross-block buffers are written-once-read-
// once per address (per-iteration slots); the one reused slot is read via
// bypass loads at the final reduce. Phase C removed (redundant per-block
// reduction); q/w/c2 in LDS. 512-thread blocks, 6 barriers total.

#define Bd 8
#define Nd 4096
#define Kd 8
#define Dd 256
#define Md (Bd*Nd)              // 32768 rows
#define NITER 3
#define EPSf 1e-8f
#define LNEPS 1e-5f
#define NCH 32                  // chunks per batch
#define CHN 128                 // n per chunk
#define GRIDN 256               // k_iter grid size (b x chunk)
#define TPB 512
#define LOGNORM -235.24826450039617f   // -0.5*256*log(2*pi)

typedef float f32x4 __attribute__((ext_vector_type(4)));
typedef short bf16x8 __attribute__((ext_vector_type(8)));
typedef unsigned short ushort_t;

// workspace float offsets (total 18,886,657 floats = 75.5 MB)
#define KEYS_OFF 0
#define VALS_OFF (Md*Dd)                 // 8388608
#define CMX_OFF  (2*Md*Dd)               // 3 slots x 2048
#define CSM_OFF  (CMX_OFF + 3*2048)
#define PMU_OFF  (CSM_OFF + 3*2048)      // 2 slots x 524288
#define PS2_OFF  (PMU_OFF + 2*524288)
#define CNT_OFF  (PS2_OFF + 2*524288)

__device__ __forceinline__ ushort_t f2bf(float f) {
    unsigned u = __float_as_uint(f);
    return (ushort_t)((u + 0x7FFFu + ((u >> 16) & 1u)) >> 16);   // RNE
}
__device__ __forceinline__ float b2f(ushort_t h) {
    return __uint_as_float(((unsigned)h) << 16);
}

// Grid barrier: release-add (flushes this block's stores to the coherent
// point via wbl2) + relaxed bypass-load spin (NO cache invalidates -> L2
// data residency survives). Monotone counter, no reset.
__device__ __forceinline__ void gbar(unsigned* cnt, unsigned target) {
    __syncthreads();   // drains vmcnt for all waves before the release
    if (threadIdx.x == 0) {
        __hip_atomic_fetch_add(cnt, 1u, __ATOMIC_RELEASE, __HIP_MEMORY_SCOPE_SYSTEM);
        while (__hip_atomic_load(cnt, __ATOMIC_RELAXED, __HIP_MEMORY_SCOPE_SYSTEM) < target)
            __builtin_amdgcn_s_sleep(2);
        asm volatile("" ::: "memory");
    }
    __syncthreads();
}

// ---------------------------------------------------------------------------
// GEMM: C[32768 x 512] = LN(emb) x [Wk||Wv]^T via split-bf16 MFMA.
// (unchanged from R4 — proven correct; 44us)
__global__ __launch_bounds__(256, 2) void k_gemm(
        const float* __restrict__ emb, const float* __restrict__ Wk,
        const float* __restrict__ Wv, const float* __restrict__ lns,
        const float* __restrict__ lnb, float* __restrict__ keys,
        float* __restrict__ vals, unsigned* __restrict__ cnt) {
    __shared__ ushort_t Ah[128 * 32], Al[128 * 32];
    __shared__ ushort_t Bh[256 * 32], Bl[256 * 32];
    __shared__ float m_s[128], r_s[128];
    const int tid = threadIdx.x, lane = tid & 63, wave = tid >> 6;
    const int row0 = blockIdx.x * 128;
    const int cb = blockIdx.y;
    const int wm = wave >> 1, wn = wave & 1;

    if (blockIdx.x == 0 && cb == 0 && tid == 0) *cnt = 0u;

    for (int rr = 0; rr < 32; ++rr) {
        const int r = wave * 32 + rr;
        const float4 e4 = ((const float4*)(emb + (size_t)(row0 + r) * Dd))[lane];
        float s = e4.x + e4.y + e4.z + e4.w;
        #pragma unroll
        for (int off = 32; off; off >>= 1) s += __shfl_xor(s, off);
        const float m = s * (1.0f / 256.0f);
        const float dx = e4.x - m, dy = e4.y - m, dz = e4.z - m, dw = e4.w - m;
        float ss = dx * dx + dy * dy + dz * dz + dw * dw;
        #pragma unroll
        for (int off = 32; off; off >>= 1) ss += __shfl_xor(ss, off);
        if (lane == 0) {
            m_s[r] = m;
            r_s[r] = 1.0f / sqrtf(ss * (1.0f / 256.0f) + LNEPS);
        }
    }
    __syncthreads();

    f32x4 acc[4][8];
    #pragma unroll
    for (int a = 0; a < 4; ++a)
        #pragma unroll
        for (int b = 0; b < 8; ++b) acc[a][b] = (f32x4)(0.0f);

    for (int jb = 0; jb < 256; jb += 32) {
        #pragma unroll
        for (int i = 0; i < 2; ++i) {
            const int p = tid + i * 256;
            const int r = p >> 2, g = p & 3;
            const float* src = emb + (size_t)(row0 + r) * Dd + jb + g * 8;
            const float4 e0 = ((const float4*)src)[0];
            const float4 e1 = ((const float4*)src)[1];
            const float m  = m_s[r];
            const float rs = r_s[r];
            const float4 sc0 = ((const float4*)(lns + jb + g * 8))[0];
            const float4 sc1 = ((const float4*)(lns + jb + g * 8))[1];
            const float4 bi0 = ((const float4*)(lnb + jb + g * 8))[0];
            const float4 bi1 = ((const float4*)(lnb + jb + g * 8))[1];
            float x[8];
            x[0] = (e0.x - m) * rs * sc0.x + bi0.x;
            x[1] = (e0.y - m) * rs * sc0.y + bi0.y;
            x[2] = (e0.z - m) * rs * sc0.z + bi0.z;
            x[3] = (e0.w - m) * rs * sc0.w + bi0.w;
            x[4] = (e1.x - m) * rs * sc1.x + bi1.x;
            x[5] = (e1.y - m) * rs * sc1.y + bi1.y;
            x[6] = (e1.z - m) * rs * sc1.z + bi1.z;
            x[7] = (e1.w - m) * rs * sc1.w + bi1.w;
            bf16x8 hv, lv;
            #pragma unroll
            for (int j = 0; j < 8; ++j) {
                const ushort_t h = f2bf(x[j]);
                hv[j] = (short)h;
                lv[j] = (short)f2bf(x[j] - b2f(h));
            }
            const int dst = r * 32 + ((g ^ ((r >> 1) & 3)) << 3);
            *(bf16x8*)&Ah[dst] = hv;
            *(bf16x8*)&Al[dst] = lv;
        }
        {
            const float* Wrow = (cb ? Wv : Wk) + (size_t)tid * 256 + jb;
            float4 wv[8];
            #pragma unroll
            for (int q = 0; q < 8; ++q) wv[q] = ((const float4*)Wrow)[q];
            #pragma unroll
            for (int g = 0; g < 4; ++g) {
                bf16x8 hv, lv;
                const float* f = (const float*)&wv[g * 2];
                #pragma unroll
                for (int e = 0; e < 8; ++e) {
                    const ushort_t h = f2bf(f[e]);
                    hv[e] = (short)h;
                    lv[e] = (short)f2bf(f[e] - b2f(h));
                }
                const int dst = tid * 32 + ((g ^ ((tid >> 1) & 3)) << 3);
                *(bf16x8*)&Bh[dst] = hv;
                *(bf16x8*)&Bl[dst] = lv;
            }
        }
        __syncthreads();

        bf16x8 bhf[8], blf[8];
        #pragma unroll
        for (int ni = 0; ni < 8; ++ni) {
            const int c = wn * 128 + ni * 16 + (lane & 15);
            const int g = lane >> 4;
            const int off = c * 32 + ((g ^ ((c >> 1) & 3)) << 3);
            bhf[ni] = *(const bf16x8*)&Bh[off];
            blf[ni] = *(const bf16x8*)&Bl[off];
        }
        #pragma unroll
        for (int mi = 0; mi < 4; ++mi) {
            const int rr = wm * 64 + mi * 16 + (lane & 15);
            const int g = lane >> 4;
            const int off = rr * 32 + ((g ^ ((rr >> 1) & 3)) << 3);
            const bf16x8 ah = *(const bf16x8*)&Ah[off];
            const bf16x8 al = *(const bf16x8*)&Al[off];
            #pragma unroll
            for (int ni = 0; ni < 8; ++ni) {
                acc[mi][ni] = __builtin_amdgcn_mfma_f32_16x16x32_bf16(ah, bhf[ni], acc[mi][ni], 0, 0, 0);
                acc[mi][ni] = __builtin_amdgcn_mfma_f32_16x16x32_bf16(ah, blf[ni], acc[mi][ni], 0, 0, 0);
                acc[mi][ni] = __builtin_amdgcn_mfma_f32_16x16x32_bf16(al, bhf[ni], acc[mi][ni], 0, 0, 0);
            }
        }
        __syncthreads();
    }
    float* outp = (cb == 0) ? keys : vals;
    #pragma unroll
    for (int mi = 0; mi < 4; ++mi) {
        const int rbase = row0 + wm * 64 + mi * 16 + ((lane >> 4) << 2);
        #pragma unroll
        for (int ni = 0; ni < 8; ++ni) {
            const int col = wn * 128 + ni * 16 + (lane & 15);
            #pragma unroll
            for (int rg = 0; rg < 4; ++rg)
                outp[(size_t)(rbase + rg) * Dd + col] = acc[mi][ni][rg];
        }
    }
}

// ---------------------------------------------------------------------------
// Iteration kernel: 256 blocks x 512 threads. Block (b=blk>>5, c=blk&31)
// owns 128 n. Per iter: A (gll + chunk stats) -> bar -> B (softmax + attn +
// mu/s2 partials) -> bar -> redundant per-block reduce (w,c2 in LDS;
// slots_out on last iter). q/w/c2 never leave LDS.
__global__ __launch_bounds__(TPB) void k_iter(
        const float* __restrict__ keys, const float* __restrict__ vals,
        const float* __restrict__ mu0, const float* __restrict__ lsig,
        const float* __restrict__ nz0, const float* __restrict__ Wq,
        const float* __restrict__ nzf, float* __restrict__ ws,
        float* __restrict__ out) {
    __shared__ float q_s[2048];          // 8 KB  [k][d]
    __shared__ float w_s[2048];          // 8 KB  [k][d]
    __shared__ float slt[2048];          // 8 KB  (init only)
    __shared__ float comb[4096];         // 16 KB (multi-use scratch)
    __shared__ float a_t[CHN * 12];      // 6 KB  [n][k], pad-12 stride
    __shared__ float c2_s[8];

    float* cmxg = ws + CMX_OFF;
    float* csmg = ws + CSM_OFF;
    float* pmug = ws + PMU_OFF;
    float* ps2g = ws + PS2_OFF;
    unsigned* cnt = (unsigned*)(ws + CNT_OFF);
    float* attn_out = out + Bd * Kd * Dd;

    const int blk = blockIdx.x, tid = threadIdx.x;
    const int b = blk >> 5, c = blk & 31, n0 = c * CHN;
    const int wave = tid >> 6, lane = tid & 63;
    unsigned ep = 0;

    // ---- init (redundant per block, no barrier): slots, w, c2, q ----
    {
        const int kk = tid >> 6, d4 = (tid & 63) * 4;
        const float4 ls = *(const float4*)&lsig[kk * 256 + d4];
        const float4 m0 = *(const float4*)&mu0[kk * 256 + d4];
        const float4 nz = *(const float4*)&nz0[(size_t)(b * 8 + kk) * 256 + d4];
        const float s0 = expf(ls.x), s1 = expf(ls.y), s2 = expf(ls.z), s3 = expf(ls.w);
        float4 sv, wv, lg;
        sv.x = m0.x + s0 * nz.x; sv.y = m0.y + s1 * nz.y;
        sv.z = m0.z + s2 * nz.z; sv.w = m0.w + s3 * nz.w;
        wv.x = 1.0f / (s0 * s0 + EPSf); wv.y = 1.0f / (s1 * s1 + EPSf);
        wv.z = 1.0f / (s2 * s2 + EPSf); wv.w = 1.0f / (s3 * s3 + EPSf);
        lg.x = logf(s0 + EPSf); lg.y = logf(s1 + EPSf);
        lg.z = logf(s2 + EPSf); lg.w = logf(s3 + EPSf);
        *(float4*)&slt[tid * 4]  = sv;
        *(float4*)&w_s[tid * 4]  = wv;
        *(float4*)&comb[tid * 4] = lg;
    }
    __syncthreads();
    {   // c2 per k: wave kk reduces comb row
        float s = comb[wave * 256 + lane]       + comb[wave * 256 + lane + 64]
                + comb[wave * 256 + lane + 128] + comb[wave * 256 + lane + 192];
        #pragma unroll
        for (int off = 32; off; off >>= 1) s += __shfl_xor(s, off);
        if (lane == 0) c2_s[wave] = LOGNORM - 0.5f * s;
    }
    {   // q[kk][d..d+3] = slots[kk] . Wq[d..d+3]
        const int kk = tid >> 6, d = (tid & 63) * 4;
        float4 acc4 = {0.0f, 0.0f, 0.0f, 0.0f};
        for (int j4 = 0; j4 < 64; ++j4) {
            const float4 s4 = *(const float4*)&slt[kk * 256 + j4 * 4];
            const float4 w0 = *(const float4*)&Wq[(size_t)(d + 0) * 256 + j4 * 4];
            const float4 w1 = *(const float4*)&Wq[(size_t)(d + 1) * 256 + j4 * 4];
            const float4 w2 = *(const float4*)&Wq[(size_t)(d + 2) * 256 + j4 * 4];
            const float4 w3 = *(const float4*)&Wq[(size_t)(d + 3) * 256 + j4 * 4];
            acc4.x += w0.x * s4.x + w0.y * s4.y + w0.z * s4.z + w0.w * s4.w;
            acc4.y += w1.x * s4.x + w1.y * s4.y + w1.z * s4.z + w1.w * s4.w;
            acc4.z += w2.x * s4.x + w2.y * s4.y + w2.z * s4.z + w2.w * s4.w;
            acc4.w += w3.x * s4.x + w3.y * s4.y + w3.z * s4.z + w3.w * s4.w;
        }
        *(float4*)&q_s[kk * 256 + d] = acc4;
    }
    __syncthreads();

    float gA = 0.0f, gB = 0.0f;
    for (int it = 0; it < NITER; ++it) {
        // ================= phase A: gll + per-chunk stats =================
        {
            const int dp = tid >> 7, nloc = tid & 127;   // D-quarter, n
            const float* kr = keys + ((size_t)(b * Nd) + n0 + nloc) * Dd + dp * 64;
            float acc[8];
            #pragma unroll
            for (int kk = 0; kk < 8; ++kk) acc[kk] = 0.0f;
            #pragma unroll
            for (int j4 = 0; j4 < 16; ++j4) {
                const float4 k4 = *(const float4*)&kr[j4 * 4];
                #pragma unroll
                for (int kk = 0; kk < 8; ++kk) {
                    const float4 q4 = *(const float4*)&q_s[kk * 256 + dp * 64 + j4 * 4];
                    const float4 w4 = *(const float4*)&w_s[kk * 256 + dp * 64 + j4 * 4];
                    float t;
                    t = k4.x - q4.x; acc[kk] += t * t * w4.x;
                    t = k4.y - q4.y; acc[kk] += t * t * w4.y;
                    t = k4.z - q4.z; acc[kk] += t * t * w4.z;
                    t = k4.w - q4.w; acc[kk] += t * t * w4.w;
                }
            }
            #pragma unroll
            for (int kk = 0; kk < 8; ++kk) comb[(dp * 8 + kk) * 128 + nloc] = acc[kk];
        }
        __syncthreads();
        {
            const int kk = wave;                 // thread owns (kk, lane) and (kk, lane+64)
            float sA = 0.0f, sB = 0.0f;
            #pragma unroll
            for (int dp = 0; dp < 4; ++dp) {
                sA += comb[(dp * 8 + kk) * 128 + lane];
                sB += comb[(dp * 8 + kk) * 128 + lane + 64];
            }
            gA = fminf(fmaxf(c2_s[kk] - 0.5f * sA, -10000.0f), 10000.0f);
            gB = fminf(fmaxf(c2_s[kk] - 0.5f * sB, -10000.0f), 10000.0f);
            float m = fmaxf(gA, gB);
            #pragma unroll
            for (int off = 32; off; off >>= 1) m = fmaxf(m, __shfl_xor(m, off));
            float se = expf(gA - m) + expf(gB - m);
            #pragma unroll
            for (int off = 32; off; off >>= 1) se += __shfl_xor(se, off);
            if (lane == 0) {
                cmxg[it * 2048 + (b * 8 + kk) * NCH + c] = m;
                csmg[it * 2048 + (b * 8 + kk) * NCH + c] = se;
            }
        }
        gbar(cnt, ++ep * GRIDN);

        // ============ phase B: softmax finalize + attn + mu/s2 ============
        {
            const int kk = wave;
            float M = -3.0e38f, S = 0.0f;
            for (int i = 0; i < NCH; ++i) {          // wave-uniform scan
                const float mi = cmxg[it * 2048 + (b * 8 + kk) * NCH + i];
                const float si = csmg[it * 2048 + (b * 8 + kk) * NCH + i];
                const float Mn = fmaxf(M, mi);
                S = S * expf(M - Mn) + si * expf(mi - Mn);
                M = Mn;
            }
            const float inv = 1.0f / S;
            const float aA = expf(gA - M) * inv;
            const float aB = expf(gB - M) * inv;
            a_t[lane * 12 + kk]        = aA;
            a_t[(lane + 64) * 12 + kk] = aB;
            if (it == NITER - 1) {
                attn_out[(size_t)(b * 8 + kk) * Nd + n0 + lane]      = aA;
                attn_out[(size_t)(b * 8 + kk) * Nd + n0 + lane + 64] = aB;
            }
        }
        __syncthreads();
        {
            const int d = tid & 255, nq = tid >> 8;   // nq in {0,1}
            const float* vb = vals + ((size_t)(b * Nd) + n0 + nq * 64) * Dd + d;
            float amu[8], as2[8];
            #pragma unroll
            for (int kk = 0; kk < 8; ++kk) { amu[kk] = 0.0f; as2[kk] = 0.0f; }
            for (int nn = 0; nn < 64; ++nn) {
                const float v = vb[(size_t)nn * Dd];
                const float v2 = v * v;
                const float4 a0 = *(const float4*)&a_t[(nq * 64 + nn) * 12];
                const float4 a1 = *(const float4*)&a_t[(nq * 64 + nn) * 12 + 4];
                amu[0] += a0.x * v; as2[0] += a0.x * v2;
                amu[1] += a0.y * v; as2[1] += a0.y * v2;
                amu[2] += a0.z * v; as2[2] += a0.z * v2;
                amu[3] += a0.w * v; as2[3] += a0.w * v2;
                amu[4] += a1.x * v; as2[4] += a1.x * v2;
                amu[5] += a1.y * v; as2[5] += a1.y * v2;
                amu[6] += a1.z * v; as2[6] += a1.z * v2;
                amu[7] += a1.w * v; as2[7] += a1.w * v2;
            }
            float* pm = pmug + (it & 1) * 524288;
            float* p2 = ps2g + (it & 1) * 524288;
            #pragma unroll
            for (int kk = 0; kk < 8; ++kk) comb[(nq * 8 + kk) * 256 + d] = amu[kk];
            __syncthreads();
            #pragma unroll
            for (int i = 0; i < 4; ++i) {
                const int kk = i * 2 + nq;
                pm[((size_t)blk * 8 + kk) * 256 + d] =
                    comb[kk * 256 + d] + comb[(8 + kk) * 256 + d];
            }
            __syncthreads();
            #pragma unroll
            for (int kk = 0; kk < 8; ++kk) comb[(nq * 8 + kk) * 256 + d] = as2[kk];
            __syncthreads();
            #pragma unroll
            for (int i = 0; i < 4; ++i) {
                const int kk = i * 2 + nq;
                p2[((size_t)blk * 8 + kk) * 256 + d] =
                    comb[kk * 256 + d] + comb[(8 + kk) * 256 + d];
            }
        }
        gbar(cnt, ++ep * GRIDN);

        // ====== redundant reduce: totals for batch b -> w,c2 (LDS) ======
        {
            const int d = tid & 255, nq = tid >> 8;
            float* pm = pmug + (it & 1) * 524288;
            float* p2 = ps2g + (it & 1) * 524288;
            #pragma unroll
            for (int i = 0; i < 4; ++i) {
                const int kk = i * 2 + nq;
                float mu = 0.0f, s2 = 0.0f;
                if (it == NITER - 1) {
                    // slot0 was cached at iter0 -> read via bypass loads
                    for (int cc = 0; cc < NCH; ++cc) {
                        const size_t o = ((size_t)((b * NCH + cc) * 8 + kk)) * 256 + d;
                        mu += __hip_atomic_load(&pm[o], __ATOMIC_RELAXED, __HIP_MEMORY_SCOPE_SYSTEM);
                        s2 += __hip_atomic_load(&p2[o], __ATOMIC_RELAXED, __HIP_MEMORY_SCOPE_SYSTEM);
                    }
                } else {
                    for (int cc = 0; cc < NCH; ++cc) {
                        const size_t o = ((size_t)((b * NCH + cc) * 8 + kk)) * 256 + d;
                        mu += pm[o];
                        s2 += p2[o];
                    }
                }
                const float sg = s2 - mu * mu;
                if (it == NITER - 1) {
                    if (c == 0)
                        out[(size_t)(b * 8 + kk) * 256 + d] =
                            mu + fmaxf(fabsf(sg), EPSf) * nzf[(size_t)(b * 8 + kk) * 256 + d];
                } else {
                    w_s[kk * 256 + d]  = 1.0f / (sg * sg + EPSf);
                    comb[kk * 256 + d] = logf(fabsf(sg) + EPSf);
                }
            }
        }
        if (it < NITER - 1) {
            __syncthreads();
            float s = comb[wave * 256 + lane]       + comb[wave * 256 + lane + 64]
                    + comb[wave * 256 + lane + 128] + comb[wave * 256 + lane + 192];
            #pragma unroll
            for (int off = 32; off; off >>= 1) s += __shfl_xor(s, off);
            if (lane == 0) c2_s[wave] = LOGNORM - 0.5f * s;
            __syncthreads();
        }
    }
}

// ---------------------------------------------------------------------------
extern "C" void kernel_launch(void* const* d_in, const int* in_sizes, int n_in,
                              void* d_out, int out_size, void* d_ws, size_t ws_size,
                              hipStream_t stream) {
    const float* emb  = (const float*)d_in[0];
    const float* mu0  = (const float*)d_in[1];
    const float* lsig = (const float*)d_in[2];
    // d_in[3] mixing_coeffs: constant per (b,k), cancels in softmax over N.
    const float* Wq   = (const float*)d_in[4];
    const float* Wk   = (const float*)d_in[5];
    const float* Wv   = (const float*)d_in[6];
    const float* lns  = (const float*)d_in[7];
    const float* lnb  = (const float*)d_in[8];
    const float* nz0  = (const float*)d_in[9];
    const float* nzf  = (const float*)d_in[10];
    // d_in[11] num_iterations == 3.

    float* ws  = (float*)d_ws;
    float* out = (float*)d_out;
    float* keys = ws + KEYS_OFF;
    float* vals = ws + VALS_OFF;
    unsigned* cnt = (unsigned*)(ws + CNT_OFF);

    k_gemm<<<dim3(256, 2), 256, 0, stream>>>(emb, Wk, Wv, lns, lnb, keys, vals, cnt);
    k_iter<<<GRIDN, TPB, 0, stream>>>(keys, vals, mu0, lsig, nz0, Wq, nzf, ws, out);
    (void)in_sizes; (void)n_in; (void)out_size; (void)ws_size;
}

// Round 6
// 359.544 us; speedup vs baseline: 1.9644x; 1.9241x over previous
//
#include <hip/hip_runtime.h>
#include <math.h>

// Probabilistic Slot Attention, B=8 N=4096 K=8 D=256, 3 iterations.
// Round 6: flash-style deferred softmax normalization fuses the gll and
// mu/s2 phases (2 barriers/iter, 5 total); dedicated reducer blocks (0..63)
// read the 4 MB of partials instead of R5's all-block redundant reduce
// (512 MB/iter -> HBM thrash, FETCH 320 MB). Cross-block buffers versioned
// per iteration; reused slot read via bypass loads. Barrier = R5's proven
// release/system add + relaxed/system bypass poll.

#define Bd 8
#define Nd 4096
#define Kd 8
#define Dd 256
#define Md (Bd*Nd)              // 32768 rows
#define NITER 3
#define EPSf 1e-8f
#define LNEPS 1e-5f
#define NCH 32                  // chunks per batch
#define CHN 128                 // n per chunk
#define GRIDN 256               // k_iter grid size (b x chunk)
#define TPB 512
#define LOGNORM -235.24826450039617f   // -0.5*256*log(2*pi)

typedef float f32x4 __attribute__((ext_vector_type(4)));
typedef short bf16x8 __attribute__((ext_vector_type(8)));
typedef unsigned short ushort_t;

// workspace float offsets
#define KEYS_OFF 0
#define VALS_OFF (Md*Dd)                 // 8388608
#define CMX_OFF  (2*Md*Dd)               // 3 slots x 2048
#define CSM_OFF  (CMX_OFF + 3*2048)
#define PMU_OFF  (CSM_OFF + 3*2048)      // 2 slots x 524288
#define PS2_OFF  (PMU_OFF + 2*524288)
#define W2_OFF   (PS2_OFF + 2*524288)    // 2 slots x 16384
#define C2B_OFF  (W2_OFF + 2*16384)      // 2 slots x 64
#define CNT_OFF  (C2B_OFF + 2*64)

__device__ __forceinline__ ushort_t f2bf(float f) {
    unsigned u = __float_as_uint(f);
    return (ushort_t)((u + 0x7FFFu + ((u >> 16) & 1u)) >> 16);   // RNE
}
__device__ __forceinline__ float b2f(ushort_t h) {
    return __uint_as_float(((unsigned)h) << 16);
}

// R5-proven grid barrier: release/system add (flush to coherent point) +
// relaxed/system bypass-load spin (no cache maintenance). Monotone counter.
__device__ __forceinline__ void gbar(unsigned* cnt, unsigned target) {
    __syncthreads();
    if (threadIdx.x == 0) {
        __hip_atomic_fetch_add(cnt, 1u, __ATOMIC_RELEASE, __HIP_MEMORY_SCOPE_SYSTEM);
        while (__hip_atomic_load(cnt, __ATOMIC_RELAXED, __HIP_MEMORY_SCOPE_SYSTEM) < target)
            __builtin_amdgcn_s_sleep(2);
        asm volatile("" ::: "memory");
    }
    __syncthreads();
}

// ---------------------------------------------------------------------------
// GEMM: C[32768 x 512] = LN(emb) x [Wk||Wv]^T via split-bf16 MFMA.
// (unchanged since R4 — proven; ~44us)
__global__ __launch_bounds__(256, 2) void k_gemm(
        const float* __restrict__ emb, const float* __restrict__ Wk,
        const float* __restrict__ Wv, const float* __restrict__ lns,
        const float* __restrict__ lnb, float* __restrict__ keys,
        float* __restrict__ vals, unsigned* __restrict__ cnt) {
    __shared__ ushort_t Ah[128 * 32], Al[128 * 32];
    __shared__ ushort_t Bh[256 * 32], Bl[256 * 32];
    __shared__ float m_s[128], r_s[128];
    const int tid = threadIdx.x, lane = tid & 63, wave = tid >> 6;
    const int row0 = blockIdx.x * 128;
    const int cb = blockIdx.y;
    const int wm = wave >> 1, wn = wave & 1;

    if (blockIdx.x == 0 && cb == 0 && tid == 0) *cnt = 0u;

    for (int rr = 0; rr < 32; ++rr) {
        const int r = wave * 32 + rr;
        const float4 e4 = ((const float4*)(emb + (size_t)(row0 + r) * Dd))[lane];
        float s = e4.x + e4.y + e4.z + e4.w;
        #pragma unroll
        for (int off = 32; off; off >>= 1) s += __shfl_xor(s, off);
        const float m = s * (1.0f / 256.0f);
        const float dx = e4.x - m, dy = e4.y - m, dz = e4.z - m, dw = e4.w - m;
        float ss = dx * dx + dy * dy + dz * dz + dw * dw;
        #pragma unroll
        for (int off = 32; off; off >>= 1) ss += __shfl_xor(ss, off);
        if (lane == 0) {
            m_s[r] = m;
            r_s[r] = 1.0f / sqrtf(ss * (1.0f / 256.0f) + LNEPS);
        }
    }
    __syncthreads();

    f32x4 acc[4][8];
    #pragma unroll
    for (int a = 0; a < 4; ++a)
        #pragma unroll
        for (int b = 0; b < 8; ++b) acc[a][b] = (f32x4)(0.0f);

    for (int jb = 0; jb < 256; jb += 32) {
        #pragma unroll
        for (int i = 0; i < 2; ++i) {
            const int p = tid + i * 256;
            const int r = p >> 2, g = p & 3;
            const float* src = emb + (size_t)(row0 + r) * Dd + jb + g * 8;
            const float4 e0 = ((const float4*)src)[0];
            const float4 e1 = ((const float4*)src)[1];
            const float m  = m_s[r];
            const float rs = r_s[r];
            const float4 sc0 = ((const float4*)(lns + jb + g * 8))[0];
            const float4 sc1 = ((const float4*)(lns + jb + g * 8))[1];
            const float4 bi0 = ((const float4*)(lnb + jb + g * 8))[0];
            const float4 bi1 = ((const float4*)(lnb + jb + g * 8))[1];
            float x[8];
            x[0] = (e0.x - m) * rs * sc0.x + bi0.x;
            x[1] = (e0.y - m) * rs * sc0.y + bi0.y;
            x[2] = (e0.z - m) * rs * sc0.z + bi0.z;
            x[3] = (e0.w - m) * rs * sc0.w + bi0.w;
            x[4] = (e1.x - m) * rs * sc1.x + bi1.x;
            x[5] = (e1.y - m) * rs * sc1.y + bi1.y;
            x[6] = (e1.z - m) * rs * sc1.z + bi1.z;
            x[7] = (e1.w - m) * rs * sc1.w + bi1.w;
            bf16x8 hv, lv;
            #pragma unroll
            for (int j = 0; j < 8; ++j) {
                const ushort_t h = f2bf(x[j]);
                hv[j] = (short)h;
                lv[j] = (short)f2bf(x[j] - b2f(h));
            }
            const int dst = r * 32 + ((g ^ ((r >> 1) & 3)) << 3);
            *(bf16x8*)&Ah[dst] = hv;
            *(bf16x8*)&Al[dst] = lv;
        }
        {
            const float* Wrow = (cb ? Wv : Wk) + (size_t)tid * 256 + jb;
            float4 wv[8];
            #pragma unroll
            for (int q = 0; q < 8; ++q) wv[q] = ((const float4*)Wrow)[q];
            #pragma unroll
            for (int g = 0; g < 4; ++g) {
                bf16x8 hv, lv;
                const float* f = (const float*)&wv[g * 2];
                #pragma unroll
                for (int e = 0; e < 8; ++e) {
                    const ushort_t h = f2bf(f[e]);
                    hv[e] = (short)h;
                    lv[e] = (short)f2bf(f[e] - b2f(h));
                }
                const int dst = tid * 32 + ((g ^ ((tid >> 1) & 3)) << 3);
                *(bf16x8*)&Bh[dst] = hv;
                *(bf16x8*)&Bl[dst] = lv;
            }
        }
        __syncthreads();

        bf16x8 bhf[8], blf[8];
        #pragma unroll
        for (int ni = 0; ni < 8; ++ni) {
            const int c = wn * 128 + ni * 16 + (lane & 15);
            const int g = lane >> 4;
            const int off = c * 32 + ((g ^ ((c >> 1) & 3)) << 3);
            bhf[ni] = *(const bf16x8*)&Bh[off];
            blf[ni] = *(const bf16x8*)&Bl[off];
        }
        #pragma unroll
        for (int mi = 0; mi < 4; ++mi) {
            const int rr = wm * 64 + mi * 16 + (lane & 15);
            const int g = lane >> 4;
            const int off = rr * 32 + ((g ^ ((rr >> 1) & 3)) << 3);
            const bf16x8 ah = *(const bf16x8*)&Ah[off];
            const bf16x8 al = *(const bf16x8*)&Al[off];
            #pragma unroll
            for (int ni = 0; ni < 8; ++ni) {
                acc[mi][ni] = __builtin_amdgcn_mfma_f32_16x16x32_bf16(ah, bhf[ni], acc[mi][ni], 0, 0, 0);
                acc[mi][ni] = __builtin_amdgcn_mfma_f32_16x16x32_bf16(ah, blf[ni], acc[mi][ni], 0, 0, 0);
                acc[mi][ni] = __builtin_amdgcn_mfma_f32_16x16x32_bf16(al, bhf[ni], acc[mi][ni], 0, 0, 0);
            }
        }
        __syncthreads();
    }
    float* outp = (cb == 0) ? keys : vals;
    #pragma unroll
    for (int mi = 0; mi < 4; ++mi) {
        const int rbase = row0 + wm * 64 + mi * 16 + ((lane >> 4) << 2);
        #pragma unroll
        for (int ni = 0; ni < 8; ++ni) {
            const int col = wn * 128 + ni * 16 + (lane & 15);
            #pragma unroll
            for (int rg = 0; rg < 4; ++rg)
                outp[(size_t)(rbase + rg) * Dd + col] = acc[mi][ni][rg];
        }
    }
}

// ---------------------------------------------------------------------------
// Iteration kernel: 256 blocks x 512 threads (1 block/CU). Block (b,c) owns
// 128 n. Per iter: AB (gll -> chunk max/sumexp -> unnormalized mu/s2
// partials) -> bar -> C (reducers 0..63 rescale+reduce -> w,c2 slots; last
// iter: all blocks normalize+write attn, reducers write slots_out) -> bar.
__global__ __launch_bounds__(TPB) void k_iter(
        const float* __restrict__ keys, const float* __restrict__ vals,
        const float* __restrict__ mu0, const float* __restrict__ lsig,
        const float* __restrict__ nz0, const float* __restrict__ Wq,
        const float* __restrict__ nzf, float* __restrict__ ws,
        float* __restrict__ out) {
    __shared__ float q_s[2048];          // 8 KB  [k][d]
    __shared__ float w_s[2048];          // 8 KB  [k][d]
    __shared__ float slt[2048];          // 8 KB  (init only)
    __shared__ float comb[4096];         // 16 KB multi-use scratch
    __shared__ float a_t[CHN * 12];      // 6 KB  [n][k] pad-12
    __shared__ float c2_s[8];

    float* cmxg = ws + CMX_OFF;
    float* csmg = ws + CSM_OFF;
    float* pmug = ws + PMU_OFF;
    float* ps2g = ws + PS2_OFF;
    float* w2g  = ws + W2_OFF;
    float* c2bg = ws + C2B_OFF;
    unsigned* cnt = (unsigned*)(ws + CNT_OFF);
    float* attn_out = out + Bd * Kd * Dd;

    const int blk = blockIdx.x, tid = threadIdx.x;
    const int b = blk >> 5, c = blk & 31, n0 = c * CHN;
    const int wave = tid >> 6, lane = tid & 63;
    unsigned ep = 0;

    // ---- init (local, no barrier): slots, w(iter0), c2(iter0), q ----
    {
        const int kk = tid >> 6, d4 = (tid & 63) * 4;
        const float4 ls = *(const float4*)&lsig[kk * 256 + d4];
        const float4 m0 = *(const float4*)&mu0[kk * 256 + d4];
        const float4 nz = *(const float4*)&nz0[(size_t)(b * 8 + kk) * 256 + d4];
        const float s0 = expf(ls.x), s1 = expf(ls.y), s2 = expf(ls.z), s3 = expf(ls.w);
        float4 sv, wv, lg;
        sv.x = m0.x + s0 * nz.x; sv.y = m0.y + s1 * nz.y;
        sv.z = m0.z + s2 * nz.z; sv.w = m0.w + s3 * nz.w;
        wv.x = 1.0f / (s0 * s0 + EPSf); wv.y = 1.0f / (s1 * s1 + EPSf);
        wv.z = 1.0f / (s2 * s2 + EPSf); wv.w = 1.0f / (s3 * s3 + EPSf);
        lg.x = logf(s0 + EPSf); lg.y = logf(s1 + EPSf);
        lg.z = logf(s2 + EPSf); lg.w = logf(s3 + EPSf);
        *(float4*)&slt[tid * 4]  = sv;
        *(float4*)&w_s[tid * 4]  = wv;
        *(float4*)&comb[tid * 4] = lg;
    }
    __syncthreads();
    {
        float s = comb[wave * 256 + lane]       + comb[wave * 256 + lane + 64]
                + comb[wave * 256 + lane + 128] + comb[wave * 256 + lane + 192];
        #pragma unroll
        for (int off = 32; off; off >>= 1) s += __shfl_xor(s, off);
        if (lane == 0) c2_s[wave] = LOGNORM - 0.5f * s;
    }
    {
        const int kk = tid >> 6, d = (tid & 63) * 4;
        float4 acc4 = {0.0f, 0.0f, 0.0f, 0.0f};
        for (int j4 = 0; j4 < 64; ++j4) {
            const float4 s4 = *(const float4*)&slt[kk * 256 + j4 * 4];
            const float4 w0 = *(const float4*)&Wq[(size_t)(d + 0) * 256 + j4 * 4];
            const float4 w1 = *(const float4*)&Wq[(size_t)(d + 1) * 256 + j4 * 4];
            const float4 w2 = *(const float4*)&Wq[(size_t)(d + 2) * 256 + j4 * 4];
            const float4 w3 = *(const float4*)&Wq[(size_t)(d + 3) * 256 + j4 * 4];
            acc4.x += w0.x * s4.x + w0.y * s4.y + w0.z * s4.z + w0.w * s4.w;
            acc4.y += w1.x * s4.x + w1.y * s4.y + w1.z * s4.z + w1.w * s4.w;
            acc4.z += w2.x * s4.x + w2.y * s4.y + w2.z * s4.z + w2.w * s4.w;
            acc4.w += w3.x * s4.x + w3.y * s4.y + w3.z * s4.z + w3.w * s4.w;
        }
        *(float4*)&q_s[kk * 256 + d] = acc4;
    }
    __syncthreads();

    for (int it = 0; it < NITER; ++it) {
        float* pm = pmug + (it & 1) * 524288;
        float* p2 = ps2g + (it & 1) * 524288;
        float* cmx = cmxg + it * 2048;
        float* csm = csmg + it * 2048;

        // ========== phase AB: gll -> chunk stats -> unnorm partials =======
        {
            const int dp = tid >> 7, nloc = tid & 127;
            const float* kr = keys + ((size_t)(b * Nd) + n0 + nloc) * Dd + dp * 64;
            float acc[8];
            #pragma unroll
            for (int kk = 0; kk < 8; ++kk) acc[kk] = 0.0f;
            #pragma unroll
            for (int j4 = 0; j4 < 16; ++j4) {
                const float4 k4 = *(const float4*)&kr[j4 * 4];
                #pragma unroll
                for (int kk = 0; kk < 8; ++kk) {
                    const float4 q4 = *(const float4*)&q_s[kk * 256 + dp * 64 + j4 * 4];
                    const float4 w4 = *(const float4*)&w_s[kk * 256 + dp * 64 + j4 * 4];
                    float t;
                    t = k4.x - q4.x; acc[kk] += t * t * w4.x;
                    t = k4.y - q4.y; acc[kk] += t * t * w4.y;
                    t = k4.z - q4.z; acc[kk] += t * t * w4.z;
                    t = k4.w - q4.w; acc[kk] += t * t * w4.w;
                }
            }
            #pragma unroll
            for (int kk = 0; kk < 8; ++kk) comb[(dp * 8 + kk) * 128 + nloc] = acc[kk];
        }
        __syncthreads();
        float mreg;
        {
            const int kk = wave;
            float sA = 0.0f, sB = 0.0f;
            #pragma unroll
            for (int dp = 0; dp < 4; ++dp) {
                sA += comb[(dp * 8 + kk) * 128 + lane];
                sB += comb[(dp * 8 + kk) * 128 + lane + 64];
            }
            const float gA = fminf(fmaxf(c2_s[kk] - 0.5f * sA, -10000.0f), 10000.0f);
            const float gB = fminf(fmaxf(c2_s[kk] - 0.5f * sB, -10000.0f), 10000.0f);
            float m = fmaxf(gA, gB);
            #pragma unroll
            for (int off = 32; off; off >>= 1) m = fmaxf(m, __shfl_xor(m, off));
            const float eA = expf(gA - m), eB = expf(gB - m);
            float se = eA + eB;
            #pragma unroll
            for (int off = 32; off; off >>= 1) se += __shfl_xor(se, off);
            a_t[lane * 12 + kk]        = eA;
            a_t[(lane + 64) * 12 + kk] = eB;
            if (lane == 0) {
                cmx[(b * 8 + kk) * NCH + c] = m;
                csm[(b * 8 + kk) * NCH + c] = se;
            }
            mreg = m;
        }
        __syncthreads();
        {
            const int d = tid & 255, nq = tid >> 8;
            const float* vb = vals + ((size_t)(b * Nd) + n0 + nq * 64) * Dd + d;
            float amu[8], as2[8];
            #pragma unroll
            for (int kk = 0; kk < 8; ++kk) { amu[kk] = 0.0f; as2[kk] = 0.0f; }
            for (int nn = 0; nn < 64; ++nn) {
                const float v = vb[(size_t)nn * Dd];
                const float v2 = v * v;
                const float4 a0 = *(const float4*)&a_t[(nq * 64 + nn) * 12];
                const float4 a1 = *(const float4*)&a_t[(nq * 64 + nn) * 12 + 4];
                amu[0] += a0.x * v; as2[0] += a0.x * v2;
                amu[1] += a0.y * v; as2[1] += a0.y * v2;
                amu[2] += a0.z * v; as2[2] += a0.z * v2;
                amu[3] += a0.w * v; as2[3] += a0.w * v2;
                amu[4] += a1.x * v; as2[4] += a1.x * v2;
                amu[5] += a1.y * v; as2[5] += a1.y * v2;
                amu[6] += a1.z * v; as2[6] += a1.z * v2;
                amu[7] += a1.w * v; as2[7] += a1.w * v2;
            }
            #pragma unroll
            for (int kk = 0; kk < 8; ++kk) comb[(nq * 8 + kk) * 256 + d] = amu[kk];
            __syncthreads();
            #pragma unroll
            for (int i = 0; i < 4; ++i) {
                const int kk = i * 2 + nq;
                pm[((size_t)blk * 8 + kk) * 256 + d] =
                    comb[kk * 256 + d] + comb[(8 + kk) * 256 + d];
            }
            __syncthreads();
            #pragma unroll
            for (int kk = 0; kk < 8; ++kk) comb[(nq * 8 + kk) * 256 + d] = as2[kk];
            __syncthreads();
            #pragma unroll
            for (int i = 0; i < 4; ++i) {
                const int kk = i * 2 + nq;
                p2[((size_t)blk * 8 + kk) * 256 + d] =
                    comb[kk * 256 + d] + comb[(8 + kk) * 256 + d];
            }
        }
        gbar(cnt, ++ep * GRIDN);

        // ================== phase C ======================================
        if (it == NITER - 1) {
            // all blocks: per-wave global M,S for (b, wave) -> write attn
            {
                const int kk = wave;
                float M = -3.0e38f, S = 0.0f;
                for (int cc = 0; cc < NCH; ++cc) {
                    const float mi = cmx[(b * 8 + kk) * NCH + cc];
                    const float si = csm[(b * 8 + kk) * NCH + cc];
                    const float Mn = fmaxf(M, mi);
                    S = S * expf(M - Mn) + si * expf(mi - Mn);
                    M = Mn;
                }
                const float scale = expf(mreg - M) / S;
                attn_out[(size_t)(b * 8 + kk) * Nd + n0 + lane] =
                    a_t[lane * 12 + kk] * scale;
                attn_out[(size_t)(b * 8 + kk) * Nd + n0 + lane + 64] =
                    a_t[(lane + 64) * 12 + kk] * scale;
            }
            // reducers: rescale+reduce partials (bypass loads: slot0 reused)
            if (blk < 64) {
                const int bb = blk >> 3, kkr = blk & 7;
                float M = -3.0e38f, S = 0.0f;
                for (int cc = 0; cc < NCH; ++cc) {
                    const float mi = cmx[(bb * 8 + kkr) * NCH + cc];
                    const float si = csm[(bb * 8 + kkr) * NCH + cc];
                    const float Mn = fmaxf(M, mi);
                    S = S * expf(M - Mn) + si * expf(mi - Mn);
                    M = Mn;
                }
                const float inv = 1.0f / S;
                const int d = tid & 255, h = tid >> 8;
                float mu = 0.0f, s2 = 0.0f;
                for (int ci = 0; ci < 16; ++ci) {
                    const int cc = h * 16 + ci;
                    const float e = expf(cmx[(bb * 8 + kkr) * NCH + cc] - M);
                    const size_t o = (((size_t)(bb * 32 + cc)) * 8 + kkr) * 256 + d;
                    mu += e * __hip_atomic_load(&pm[o], __ATOMIC_RELAXED, __HIP_MEMORY_SCOPE_SYSTEM);
                    s2 += e * __hip_atomic_load(&p2[o], __ATOMIC_RELAXED, __HIP_MEMORY_SCOPE_SYSTEM);
                }
                comb[h * 256 + d] = mu;
                comb[512 + h * 256 + d] = s2;
                __syncthreads();
                if (tid < 256) {
                    const float mt = (comb[tid] + comb[256 + tid]) * inv;
                    const float st = (comb[512 + tid] + comb[768 + tid]) * inv;
                    const float sg = st - mt * mt;
                    out[(size_t)(bb * 8 + kkr) * 256 + tid] =
                        mt + fmaxf(fabsf(sg), EPSf) * nzf[(size_t)(bb * 8 + kkr) * 256 + tid];
                }
            }
        } else {
            if (blk < 64) {
                const int bb = blk >> 3, kkr = blk & 7;
                float M = -3.0e38f, S = 0.0f;
                for (int cc = 0; cc < NCH; ++cc) {
                    const float mi = cmx[(bb * 8 + kkr) * NCH + cc];
                    const float si = csm[(bb * 8 + kkr) * NCH + cc];
                    const float Mn = fmaxf(M, mi);
                    S = S * expf(M - Mn) + si * expf(mi - Mn);
                    M = Mn;
                }
                const float inv = 1.0f / S;
                const int d = tid & 255, h = tid >> 8;
                float mu = 0.0f, s2 = 0.0f;
                for (int ci = 0; ci < 16; ++ci) {
                    const int cc = h * 16 + ci;
                    const float e = expf(cmx[(bb * 8 + kkr) * NCH + cc] - M);
                    const size_t o = (((size_t)(bb * 32 + cc)) * 8 + kkr) * 256 + d;
                    mu += e * pm[o];
                    s2 += e * p2[o];
                }
                comb[h * 256 + d] = mu;
                comb[512 + h * 256 + d] = s2;
                __syncthreads();
                if (tid < 256) {
                    const float mt = (comb[tid] + comb[256 + tid]) * inv;
                    const float st = (comb[512 + tid] + comb[768 + tid]) * inv;
                    const float sg = st - mt * mt;
                    w2g[it * 16384 + (bb * 8 + kkr) * 256 + tid] = 1.0f / (sg * sg + EPSf);
                    comb[1024 + tid] = logf(fabsf(sg) + EPSf);
                }
                __syncthreads();
                if (wave == 0) {
                    float s = comb[1024 + lane]       + comb[1024 + lane + 64]
                            + comb[1024 + lane + 128] + comb[1024 + lane + 192];
                    #pragma unroll
                    for (int off = 32; off; off >>= 1) s += __shfl_xor(s, off);
                    if (lane == 0)
                        c2bg[it * 64 + bb * 8 + kkr] = LOGNORM - 0.5f * s;
                }
            }
            gbar(cnt, ++ep * GRIDN);
            // all blocks: reload w, c2 for next iteration (fresh addresses)
            {
                const int kk = tid >> 6, d4 = (tid & 63) * 4;
                *(float4*)&w_s[tid * 4] =
                    *(const float4*)&w2g[it * 16384 + (b * 8 + kk) * 256 + d4];
            }
            if (tid < 8) c2_s[tid] = c2bg[it * 64 + b * 8 + tid];
            __syncthreads();
        }
    }
}

// ---------------------------------------------------------------------------
extern "C" void kernel_launch(void* const* d_in, const int* in_sizes, int n_in,
                              void* d_out, int out_size, void* d_ws, size_t ws_size,
                              hipStream_t stream) {
    const float* emb  = (const float*)d_in[0];
    const float* mu0  = (const float*)d_in[1];
    const float* lsig = (const float*)d_in[2];
    // d_in[3] mixing_coeffs: constant per (b,k), cancels in softmax over N.
    const float* Wq   = (const float*)d_in[4];
    const float* Wk   = (const float*)d_in[5];
    const float* Wv   = (const float*)d_in[6];
    const float* lns  = (const float*)d_in[7];
    const float* lnb  = (const float*)d_in[8];
    const float* nz0  = (const float*)d_in[9];
    const float* nzf  = (const float*)d_in[10];
    // d_in[11] num_iterations == 3.

    float* ws  = (float*)d_ws;
    float* out = (float*)d_out;
    float* keys = ws + KEYS_OFF;
    float* vals = ws + VALS_OFF;
    unsigned* cnt = (unsigned*)(ws + CNT_OFF);

    k_gemm<<<dim3(256, 2), 256, 0, stream>>>(emb, Wk, Wv, lns, lnb, keys, vals, cnt);
    k_iter<<<GRIDN, TPB, 0, stream>>>(keys, vals, mu0, lsig, nz0, Wq, nzf, ws, out);
    (void)in_sizes; (void)n_in; (void)out_size; (void)ws_size;
}

// Round 7
// 319.675 us; speedup vs baseline: 2.2094x; 1.1247x over previous
//
#include <hip/hip_runtime.h>
#include <math.h>

// Probabilistic Slot Attention, B=8 N=4096 K=8 D=256, 3 iterations.
// Round 7: (1) grid barrier reworked from single-counter fetch_add (256
// serialized same-address RMWs at the coherent point) to fan-in/fan-out:
// per-block release flags on distinct lines + master(block 255) poll +
// release 'go' broadcast. (2) Phase A remapped: wave owns a 32-d strip
// (q/w LDS reads stay wave-uniform broadcasts), each lane computes 2 n ->
// halves phase-A ds_read issue. Dataflow/coherence recipe unchanged from
// R6 (versioned slots, bypass loads on the one reused slot).

#define Bd 8
#define Nd 4096
#define Kd 8
#define Dd 256
#define Md (Bd*Nd)              // 32768 rows
#define NITER 3
#define EPSf 1e-8f
#define LNEPS 1e-5f
#define NCH 32                  // chunks per batch
#define CHN 128                 // n per chunk
#define GRIDN 256               // k_iter grid size (b x chunk)
#define TPB 512
#define MASTER (GRIDN-1)
#define LOGNORM -235.24826450039617f   // -0.5*256*log(2*pi)

typedef float f32x4 __attribute__((ext_vector_type(4)));
typedef short bf16x8 __attribute__((ext_vector_type(8)));
typedef unsigned short ushort_t;

// workspace float offsets
#define KEYS_OFF 0
#define VALS_OFF (Md*Dd)                 // 8388608
#define CMX_OFF  (2*Md*Dd)               // 3 slots x 2048
#define CSM_OFF  (CMX_OFF + 3*2048)
#define PMU_OFF  (CSM_OFF + 3*2048)      // 2 slots x 524288
#define PS2_OFF  (PMU_OFF + 2*524288)
#define W2_OFF   (PS2_OFF + 2*524288)    // 2 slots x 16384
#define C2B_OFF  (W2_OFF + 2*16384)      // 2 slots x 64
#define FLG_OFF  (C2B_OFF + 2*64)        // u32 flags[256*16] + go

__device__ __forceinline__ ushort_t f2bf(float f) {
    unsigned u = __float_as_uint(f);
    return (ushort_t)((u + 0x7FFFu + ((u >> 16) & 1u)) >> 16);   // RNE
}
__device__ __forceinline__ float b2f(ushort_t h) {
    return __uint_as_float(((unsigned)h) << 16);
}

// Fan-in/fan-out grid barrier. Arrival: release-store own flag (flushes
// this block's writes to the coherent point before flag visibility).
// Master polls all flags (relaxed bypass loads, no cache maintenance),
// then release-stores 'go'. Others poll 'go'. Monotone epochs, no reset.
__device__ __forceinline__ void gbar(unsigned* flags, unsigned ep) {
    __syncthreads();
    if (blockIdx.x == MASTER) {
        if (threadIdx.x == 0)
            __hip_atomic_store(&flags[MASTER * 16], ep, __ATOMIC_RELEASE,
                               __HIP_MEMORY_SCOPE_SYSTEM);
        if (threadIdx.x < GRIDN) {
            while (__hip_atomic_load(&flags[threadIdx.x * 16], __ATOMIC_RELAXED,
                                     __HIP_MEMORY_SCOPE_SYSTEM) < ep)
                __builtin_amdgcn_s_sleep(1);
        }
        __syncthreads();
        if (threadIdx.x == 0)
            __hip_atomic_store(&flags[GRIDN * 16], ep, __ATOMIC_RELEASE,
                               __HIP_MEMORY_SCOPE_SYSTEM);
        asm volatile("" ::: "memory");
    } else {
        if (threadIdx.x == 0) {
            __hip_atomic_store(&flags[blockIdx.x * 16], ep, __ATOMIC_RELEASE,
                               __HIP_MEMORY_SCOPE_SYSTEM);
            while (__hip_atomic_load(&flags[GRIDN * 16], __ATOMIC_RELAXED,
                                     __HIP_MEMORY_SCOPE_SYSTEM) < ep)
                __builtin_amdgcn_s_sleep(1);
            asm volatile("" ::: "memory");
        }
        __syncthreads();
    }
}

// ---------------------------------------------------------------------------
// GEMM: C[32768 x 512] = LN(emb) x [Wk||Wv]^T via split-bf16 MFMA.
// (unchanged since R4 — proven; ~44us). Also zeroes the barrier flags.
__global__ __launch_bounds__(256, 2) void k_gemm(
        const float* __restrict__ emb, const float* __restrict__ Wk,
        const float* __restrict__ Wv, const float* __restrict__ lns,
        const float* __restrict__ lnb, float* __restrict__ keys,
        float* __restrict__ vals, unsigned* __restrict__ flags) {
    __shared__ ushort_t Ah[128 * 32], Al[128 * 32];
    __shared__ ushort_t Bh[256 * 32], Bl[256 * 32];
    __shared__ float m_s[128], r_s[128];
    const int tid = threadIdx.x, lane = tid & 63, wave = tid >> 6;
    const int row0 = blockIdx.x * 128;
    const int cb = blockIdx.y;
    const int wm = wave >> 1, wn = wave & 1;

    if (blockIdx.x == 0 && cb == 0) {          // zero barrier flags + go
        if (tid < GRIDN) flags[tid * 16] = 0u;
        if (tid == 0) flags[GRIDN * 16] = 0u;
    }

    for (int rr = 0; rr < 32; ++rr) {
        const int r = wave * 32 + rr;
        const float4 e4 = ((const float4*)(emb + (size_t)(row0 + r) * Dd))[lane];
        float s = e4.x + e4.y + e4.z + e4.w;
        #pragma unroll
        for (int off = 32; off; off >>= 1) s += __shfl_xor(s, off);
        const float m = s * (1.0f / 256.0f);
        const float dx = e4.x - m, dy = e4.y - m, dz = e4.z - m, dw = e4.w - m;
        float ss = dx * dx + dy * dy + dz * dz + dw * dw;
        #pragma unroll
        for (int off = 32; off; off >>= 1) ss += __shfl_xor(ss, off);
        if (lane == 0) {
            m_s[r] = m;
            r_s[r] = 1.0f / sqrtf(ss * (1.0f / 256.0f) + LNEPS);
        }
    }
    __syncthreads();

    f32x4 acc[4][8];
    #pragma unroll
    for (int a = 0; a < 4; ++a)
        #pragma unroll
        for (int b = 0; b < 8; ++b) acc[a][b] = (f32x4)(0.0f);

    for (int jb = 0; jb < 256; jb += 32) {
        #pragma unroll
        for (int i = 0; i < 2; ++i) {
            const int p = tid + i * 256;
            const int r = p >> 2, g = p & 3;
            const float* src = emb + (size_t)(row0 + r) * Dd + jb + g * 8;
            const float4 e0 = ((const float4*)src)[0];
            const float4 e1 = ((const float4*)src)[1];
            const float m  = m_s[r];
            const float rs = r_s[r];
            const float4 sc0 = ((const float4*)(lns + jb + g * 8))[0];
            const float4 sc1 = ((const float4*)(lns + jb + g * 8))[1];
            const float4 bi0 = ((const float4*)(lnb + jb + g * 8))[0];
            const float4 bi1 = ((const float4*)(lnb + jb + g * 8))[1];
            float x[8];
            x[0] = (e0.x - m) * rs * sc0.x + bi0.x;
            x[1] = (e0.y - m) * rs * sc0.y + bi0.y;
            x[2] = (e0.z - m) * rs * sc0.z + bi0.z;
            x[3] = (e0.w - m) * rs * sc0.w + bi0.w;
            x[4] = (e1.x - m) * rs * sc1.x + bi1.x;
            x[5] = (e1.y - m) * rs * sc1.y + bi1.y;
            x[6] = (e1.z - m) * rs * sc1.z + bi1.z;
            x[7] = (e1.w - m) * rs * sc1.w + bi1.w;
            bf16x8 hv, lv;
            #pragma unroll
            for (int j = 0; j < 8; ++j) {
                const ushort_t h = f2bf(x[j]);
                hv[j] = (short)h;
                lv[j] = (short)f2bf(x[j] - b2f(h));
            }
            const int dst = r * 32 + ((g ^ ((r >> 1) & 3)) << 3);
            *(bf16x8*)&Ah[dst] = hv;
            *(bf16x8*)&Al[dst] = lv;
        }
        {
            const float* Wrow = (cb ? Wv : Wk) + (size_t)tid * 256 + jb;
            float4 wv[8];
            #pragma unroll
            for (int q = 0; q < 8; ++q) wv[q] = ((const float4*)Wrow)[q];
            #pragma unroll
            for (int g = 0; g < 4; ++g) {
                bf16x8 hv, lv;
                const float* f = (const float*)&wv[g * 2];
                #pragma unroll
                for (int e = 0; e < 8; ++e) {
                    const ushort_t h = f2bf(f[e]);
                    hv[e] = (short)h;
                    lv[e] = (short)f2bf(f[e] - b2f(h));
                }
                const int dst = tid * 32 + ((g ^ ((tid >> 1) & 3)) << 3);
                *(bf16x8*)&Bh[dst] = hv;
                *(bf16x8*)&Bl[dst] = lv;
            }
        }
        __syncthreads();

        bf16x8 bhf[8], blf[8];
        #pragma unroll
        for (int ni = 0; ni < 8; ++ni) {
            const int c = wn * 128 + ni * 16 + (lane & 15);
            const int g = lane >> 4;
            const int off = c * 32 + ((g ^ ((c >> 1) & 3)) << 3);
            bhf[ni] = *(const bf16x8*)&Bh[off];
            blf[ni] = *(const bf16x8*)&Bl[off];
        }
        #pragma unroll
        for (int mi = 0; mi < 4; ++mi) {
            const int rr = wm * 64 + mi * 16 + (lane & 15);
            const int g = lane >> 4;
            const int off = rr * 32 + ((g ^ ((rr >> 1) & 3)) << 3);
            const bf16x8 ah = *(const bf16x8*)&Ah[off];
            const bf16x8 al = *(const bf16x8*)&Al[off];
            #pragma unroll
            for (int ni = 0; ni < 8; ++ni) {
                acc[mi][ni] = __builtin_amdgcn_mfma_f32_16x16x32_bf16(ah, bhf[ni], acc[mi][ni], 0, 0, 0);
                acc[mi][ni] = __builtin_amdgcn_mfma_f32_16x16x32_bf16(ah, blf[ni], acc[mi][ni], 0, 0, 0);
                acc[mi][ni] = __builtin_amdgcn_mfma_f32_16x16x32_bf16(al, bhf[ni], acc[mi][ni], 0, 0, 0);
            }
        }
        __syncthreads();
    }
    float* outp = (cb == 0) ? keys : vals;
    #pragma unroll
    for (int mi = 0; mi < 4; ++mi) {
        const int rbase = row0 + wm * 64 + mi * 16 + ((lane >> 4) << 2);
        #pragma unroll
        for (int ni = 0; ni < 8; ++ni) {
            const int col = wn * 128 + ni * 16 + (lane & 15);
            #pragma unroll
            for (int rg = 0; rg < 4; ++rg)
                outp[(size_t)(rbase + rg) * Dd + col] = acc[mi][ni][rg];
        }
    }
}

// ---------------------------------------------------------------------------
// Iteration kernel: 256 blocks x 512 threads (1 block/CU).
__global__ __launch_bounds__(TPB) void k_iter(
        const float* __restrict__ keys, const float* __restrict__ vals,
        const float* __restrict__ mu0, const float* __restrict__ lsig,
        const float* __restrict__ nz0, const float* __restrict__ Wq,
        const float* __restrict__ nzf, float* __restrict__ ws,
        float* __restrict__ out) {
    __shared__ float q_s[2048];          // 8 KB  [k][d]
    __shared__ float w_s[2048];          // 8 KB  [k][d]
    __shared__ float slt[2048];          // 8 KB  (init only)
    __shared__ float comb[8192];         // 32 KB multi-use scratch
    __shared__ float a_t[CHN * 12];      // 6 KB  [n][k] pad-12
    __shared__ float c2_s[8];

    float* cmxg = ws + CMX_OFF;
    float* csmg = ws + CSM_OFF;
    float* pmug = ws + PMU_OFF;
    float* ps2g = ws + PS2_OFF;
    float* w2g  = ws + W2_OFF;
    float* c2bg = ws + C2B_OFF;
    unsigned* flags = (unsigned*)(ws + FLG_OFF);
    float* attn_out = out + Bd * Kd * Dd;

    const int blk = blockIdx.x, tid = threadIdx.x;
    const int b = blk >> 5, c = blk & 31, n0 = c * CHN;
    const int wave = tid >> 6, lane = tid & 63;
    unsigned ep = 0;

    // ---- init (local, no barrier): slots, w(iter0), c2(iter0), q ----
    {
        const int kk = tid >> 6, d4 = (tid & 63) * 4;
        const float4 ls = *(const float4*)&lsig[kk * 256 + d4];
        const float4 m0 = *(const float4*)&mu0[kk * 256 + d4];
        const float4 nz = *(const float4*)&nz0[(size_t)(b * 8 + kk) * 256 + d4];
        const float s0 = expf(ls.x), s1 = expf(ls.y), s2 = expf(ls.z), s3 = expf(ls.w);
        float4 sv, wv, lg;
        sv.x = m0.x + s0 * nz.x; sv.y = m0.y + s1 * nz.y;
        sv.z = m0.z + s2 * nz.z; sv.w = m0.w + s3 * nz.w;
        wv.x = 1.0f / (s0 * s0 + EPSf); wv.y = 1.0f / (s1 * s1 + EPSf);
        wv.z = 1.0f / (s2 * s2 + EPSf); wv.w = 1.0f / (s3 * s3 + EPSf);
        lg.x = logf(s0 + EPSf); lg.y = logf(s1 + EPSf);
        lg.z = logf(s2 + EPSf); lg.w = logf(s3 + EPSf);
        *(float4*)&slt[tid * 4]  = sv;
        *(float4*)&w_s[tid * 4]  = wv;
        *(float4*)&comb[tid * 4] = lg;
    }
    __syncthreads();
    {
        float s = comb[wave * 256 + lane]       + comb[wave * 256 + lane + 64]
                + comb[wave * 256 + lane + 128] + comb[wave * 256 + lane + 192];
        #pragma unroll
        for (int off = 32; off; off >>= 1) s += __shfl_xor(s, off);
        if (lane == 0) c2_s[wave] = LOGNORM - 0.5f * s;
    }
    {
        const int kk = tid >> 6, d = (tid & 63) * 4;
        float4 acc4 = {0.0f, 0.0f, 0.0f, 0.0f};
        for (int j4 = 0; j4 < 64; ++j4) {
            const float4 s4 = *(const float4*)&slt[kk * 256 + j4 * 4];
            const float4 w0 = *(const float4*)&Wq[(size_t)(d + 0) * 256 + j4 * 4];
            const float4 w1 = *(const float4*)&Wq[(size_t)(d + 1) * 256 + j4 * 4];
            const float4 w2 = *(const float4*)&Wq[(size_t)(d + 2) * 256 + j4 * 4];
            const float4 w3 = *(const float4*)&Wq[(size_t)(d + 3) * 256 + j4 * 4];
            acc4.x += w0.x * s4.x + w0.y * s4.y + w0.z * s4.z + w0.w * s4.w;
            acc4.y += w1.x * s4.x + w1.y * s4.y + w1.z * s4.z + w1.w * s4.w;
            acc4.z += w2.x * s4.x + w2.y * s4.y + w2.z * s4.z + w2.w * s4.w;
            acc4.w += w3.x * s4.x + w3.y * s4.y + w3.z * s4.z + w3.w * s4.w;
        }
        *(float4*)&q_s[kk * 256 + d] = acc4;
    }
    __syncthreads();

    for (int it = 0; it < NITER; ++it) {
        float* pm = pmug + (it & 1) * 524288;
        float* p2 = ps2g + (it & 1) * 524288;
        float* cmx = cmxg + it * 2048;
        float* csm = csmg + it * 2048;

        // ===== phase AB part 1: gll (wave = 32-d strip, 2 n per lane) =====
        {
            const int nn0 = n0 + lane * 2;
            const float* kr0 = keys + ((size_t)(b * Nd) + nn0) * Dd + wave * 32;
            const float* kr1 = kr0 + Dd;
            float acc0[8], acc1[8];
            #pragma unroll
            for (int kk = 0; kk < 8; ++kk) { acc0[kk] = 0.0f; acc1[kk] = 0.0f; }
            #pragma unroll
            for (int j4 = 0; j4 < 8; ++j4) {
                const float4 kA = *(const float4*)&kr0[j4 * 4];
                const float4 kB = *(const float4*)&kr1[j4 * 4];
                #pragma unroll
                for (int kk = 0; kk < 8; ++kk) {
                    const float4 q4 = *(const float4*)&q_s[kk * 256 + wave * 32 + j4 * 4];
                    const float4 w4 = *(const float4*)&w_s[kk * 256 + wave * 32 + j4 * 4];
                    float t;
                    t = kA.x - q4.x; acc0[kk] += t * t * w4.x;
                    t = kA.y - q4.y; acc0[kk] += t * t * w4.y;
                    t = kA.z - q4.z; acc0[kk] += t * t * w4.z;
                    t = kA.w - q4.w; acc0[kk] += t * t * w4.w;
                    t = kB.x - q4.x; acc1[kk] += t * t * w4.x;
                    t = kB.y - q4.y; acc1[kk] += t * t * w4.y;
                    t = kB.z - q4.z; acc1[kk] += t * t * w4.z;
                    t = kB.w - q4.w; acc1[kk] += t * t * w4.w;
                }
            }
            #pragma unroll
            for (int kk = 0; kk < 8; ++kk) {
                float2 p; p.x = acc0[kk]; p.y = acc1[kk];
                *(float2*)&comb[(wave * 8 + kk) * 128 + lane * 2] = p;
            }
        }
        __syncthreads();
        float mreg;
        {
            const int kk = wave;
            float sA = 0.0f, sB = 0.0f;
            #pragma unroll
            for (int dsv = 0; dsv < 8; ++dsv) {
                sA += comb[(dsv * 8 + kk) * 128 + lane];
                sB += comb[(dsv * 8 + kk) * 128 + lane + 64];
            }
            const float gA = fminf(fmaxf(c2_s[kk] - 0.5f * sA, -10000.0f), 10000.0f);
            const float gB = fminf(fmaxf(c2_s[kk] - 0.5f * sB, -10000.0f), 10000.0f);
            float m = fmaxf(gA, gB);
            #pragma unroll
            for (int off = 32; off; off >>= 1) m = fmaxf(m, __shfl_xor(m, off));
            const float eA = expf(gA - m), eB = expf(gB - m);
            float se = eA + eB;
            #pragma unroll
            for (int off = 32; off; off >>= 1) se += __shfl_xor(se, off);
            a_t[lane * 12 + kk]        = eA;
            a_t[(lane + 64) * 12 + kk] = eB;
            if (lane == 0) {
                cmx[(b * 8 + kk) * NCH + c] = m;
                csm[(b * 8 + kk) * NCH + c] = se;
            }
            mreg = m;
        }
        __syncthreads();
        // ===== phase AB part 2: unnormalized mu/s2 partials =====
        {
            const int d = tid & 255, nq = tid >> 8;
            const float* vb = vals + ((size_t)(b * Nd) + n0 + nq * 64) * Dd + d;
            float amu[8], as2[8];
            #pragma unroll
            for (int kk = 0; kk < 8; ++kk) { amu[kk] = 0.0f; as2[kk] = 0.0f; }
            for (int nn = 0; nn < 64; ++nn) {
                const float v = vb[(size_t)nn * Dd];
                const float v2 = v * v;
                const float4 a0 = *(const float4*)&a_t[(nq * 64 + nn) * 12];
                const float4 a1 = *(const float4*)&a_t[(nq * 64 + nn) * 12 + 4];
                amu[0] += a0.x * v; as2[0] += a0.x * v2;
                amu[1] += a0.y * v; as2[1] += a0.y * v2;
                amu[2] += a0.z * v; as2[2] += a0.z * v2;
                amu[3] += a0.w * v; as2[3] += a0.w * v2;
                amu[4] += a1.x * v; as2[4] += a1.x * v2;
                amu[5] += a1.y * v; as2[5] += a1.y * v2;
                amu[6] += a1.z * v; as2[6] += a1.z * v2;
                amu[7] += a1.w * v; as2[7] += a1.w * v2;
            }
            #pragma unroll
            for (int kk = 0; kk < 8; ++kk) comb[(nq * 8 + kk) * 256 + d] = amu[kk];
            __syncthreads();
            #pragma unroll
            for (int i = 0; i < 4; ++i) {
                const int kk = i * 2 + nq;
                pm[((size_t)blk * 8 + kk) * 256 + d] =
                    comb[kk * 256 + d] + comb[(8 + kk) * 256 + d];
            }
            __syncthreads();
            #pragma unroll
            for (int kk = 0; kk < 8; ++kk) comb[(nq * 8 + kk) * 256 + d] = as2[kk];
            __syncthreads();
            #pragma unroll
            for (int i = 0; i < 4; ++i) {
                const int kk = i * 2 + nq;
                p2[((size_t)blk * 8 + kk) * 256 + d] =
                    comb[kk * 256 + d] + comb[(8 + kk) * 256 + d];
            }
        }
        gbar(flags, ++ep);

        // ================== phase C ======================================
        if (it == NITER - 1) {
            {
                const int kk = wave;
                float M = -3.0e38f, S = 0.0f;
                for (int cc = 0; cc < NCH; ++cc) {
                    const float mi = cmx[(b * 8 + kk) * NCH + cc];
                    const float si = csm[(b * 8 + kk) * NCH + cc];
                    const float Mn = fmaxf(M, mi);
                    S = S * expf(M - Mn) + si * expf(mi - Mn);
                    M = Mn;
                }
                const float scale = expf(mreg - M) / S;
                attn_out[(size_t)(b * 8 + kk) * Nd + n0 + lane] =
                    a_t[lane * 12 + kk] * scale;
                attn_out[(size_t)(b * 8 + kk) * Nd + n0 + lane + 64] =
                    a_t[(lane + 64) * 12 + kk] * scale;
            }
            if (blk < 64) {
                const int bb = blk >> 3, kkr = blk & 7;
                float M = -3.0e38f, S = 0.0f;
                for (int cc = 0; cc < NCH; ++cc) {
                    const float mi = cmx[(bb * 8 + kkr) * NCH + cc];
                    const float si = csm[(bb * 8 + kkr) * NCH + cc];
                    const float Mn = fmaxf(M, mi);
                    S = S * expf(M - Mn) + si * expf(mi - Mn);
                    M = Mn;
                }
                const float inv = 1.0f / S;
                const int d = tid & 255, h = tid >> 8;
                float mu = 0.0f, s2 = 0.0f;
                for (int ci = 0; ci < 16; ++ci) {
                    const int cc = h * 16 + ci;
                    const float e = expf(cmx[(bb * 8 + kkr) * NCH + cc] - M);
                    const size_t o = (((size_t)(bb * 32 + cc)) * 8 + kkr) * 256 + d;
                    mu += e * __hip_atomic_load(&pm[o], __ATOMIC_RELAXED, __HIP_MEMORY_SCOPE_SYSTEM);
                    s2 += e * __hip_atomic_load(&p2[o], __ATOMIC_RELAXED, __HIP_MEMORY_SCOPE_SYSTEM);
                }
                comb[h * 256 + d] = mu;
                comb[512 + h * 256 + d] = s2;
                __syncthreads();
                if (tid < 256) {
                    const float mt = (comb[tid] + comb[256 + tid]) * inv;
                    const float st = (comb[512 + tid] + comb[768 + tid]) * inv;
                    const float sg = st - mt * mt;
                    out[(size_t)(bb * 8 + kkr) * 256 + tid] =
                        mt + fmaxf(fabsf(sg), EPSf) * nzf[(size_t)(bb * 8 + kkr) * 256 + tid];
                }
            }
        } else {
            if (blk < 64) {
                const int bb = blk >> 3, kkr = blk & 7;
                float M = -3.0e38f, S = 0.0f;
                for (int cc = 0; cc < NCH; ++cc) {
                    const float mi = cmx[(bb * 8 + kkr) * NCH + cc];
                    const float si = csm[(bb * 8 + kkr) * NCH + cc];
                    const float Mn = fmaxf(M, mi);
                    S = S * expf(M - Mn) + si * expf(mi - Mn);
                    M = Mn;
                }
                const float inv = 1.0f / S;
                const int d = tid & 255, h = tid >> 8;
                float mu = 0.0f, s2 = 0.0f;
                for (int ci = 0; ci < 16; ++ci) {
                    const int cc = h * 16 + ci;
                    const float e = expf(cmx[(bb * 8 + kkr) * NCH + cc] - M);
                    const size_t o = (((size_t)(bb * 32 + cc)) * 8 + kkr) * 256 + d;
                    mu += e * pm[o];
                    s2 += e * p2[o];
                }
                comb[h * 256 + d] = mu;
                comb[512 + h * 256 + d] = s2;
                __syncthreads();
                if (tid < 256) {
                    const float mt = (comb[tid] + comb[256 + tid]) * inv;
                    const float st = (comb[512 + tid] + comb[768 + tid]) * inv;
                    const float sg = st - mt * mt;
                    w2g[it * 16384 + (bb * 8 + kkr) * 256 + tid] = 1.0f / (sg * sg + EPSf);
                    comb[1024 + tid] = logf(fabsf(sg) + EPSf);
                }
                __syncthreads();
                if (wave == 0) {
                    float s = comb[1024 + lane]       + comb[1024 + lane + 64]
                            + comb[1024 + lane + 128] + comb[1024 + lane + 192];
                    #pragma unroll
                    for (int off = 32; off; off >>= 1) s += __shfl_xor(s, off);
                    if (lane == 0)
                        c2bg[it * 64 + bb * 8 + kkr] = LOGNORM - 0.5f * s;
                }
            }
            gbar(flags, ++ep);
            {
                const int kk = tid >> 6, d4 = (tid & 63) * 4;
                *(float4*)&w_s[tid * 4] =
                    *(const float4*)&w2g[it * 16384 + (b * 8 + kk) * 256 + d4];
            }
            if (tid < 8) c2_s[tid] = c2bg[it * 64 + b * 8 + tid];
            __syncthreads();
        }
    }
}

// ---------------------------------------------------------------------------
extern "C" void kernel_launch(void* const* d_in, const int* in_sizes, int n_in,
                              void* d_out, int out_size, void* d_ws, size_t ws_size,
                              hipStream_t stream) {
    const float* emb  = (const float*)d_in[0];
    const float* mu0  = (const float*)d_in[1];
    const float* lsig = (const float*)d_in[2];
    // d_in[3] mixing_coeffs: constant per (b,k), cancels in softmax over N.
    const float* Wq   = (const float*)d_in[4];
    const float* Wk   = (const float*)d_in[5];
    const float* Wv   = (const float*)d_in[6];
    const float* lns  = (const float*)d_in[7];
    const float* lnb  = (const float*)d_in[8];
    const float* nz0  = (const float*)d_in[9];
    const float* nzf  = (const float*)d_in[10];
    // d_in[11] num_iterations == 3.

    float* ws  = (float*)d_ws;
    float* out = (float*)d_out;
    float* keys = ws + KEYS_OFF;
    float* vals = ws + VALS_OFF;
    unsigned* flags = (unsigned*)(ws + FLG_OFF);

    k_gemm<<<dim3(256, 2), 256, 0, stream>>>(emb, Wk, Wv, lns, lnb, keys, vals, flags);
    k_iter<<<GRIDN, TPB, 0, stream>>>(keys, vals, mu0, lsig, nz0, Wq, nzf, ws, out);
    (void)in_sizes; (void)n_in; (void)out_size; (void)ws_size;
}